// Round 23
// baseline (416.446 us; speedup 1.0000x reference)
//
#include <hip/hip_runtime.h>
#include <hip/hip_bf16.h>
#include <math.h>

typedef __attribute__((ext_vector_type(4))) float floatx4;
typedef __attribute__((ext_vector_type(8))) __bf16 bfloatx8;
typedef __attribute__((ext_vector_type(8))) unsigned short ushortx8;

static __device__ __forceinline__ unsigned short f2bf(float f) {
  __hip_bfloat16 h = __float2bfloat16(f);
  return *reinterpret_cast<unsigned short*>(&h);
}

static __device__ __forceinline__ void gload16(const void* g, void* l) {
  __builtin_amdgcn_global_load_lds(
      (const __attribute__((address_space(1))) unsigned int*)g,
      (__attribute__((address_space(3))) unsigned int*)l, 16, 0, 0);
}

#define S_BARRIER() __builtin_amdgcn_s_barrier()
#define WAIT_VM(n)  do { asm volatile("s_waitcnt vmcnt(" #n ")" ::: "memory"); __builtin_amdgcn_sched_barrier(0); } while (0)

// sE row stride (f32) for GEMM epilogues (R18/R19 bank-conflict fix).
#define ESTR 132

// ===== fused prep (R22-proven): [0,4096) w1-T, [4096,8192) w2-T, [8192,12288) lora =====
__global__ __launch_bounds__(256) void prep_kernel(const float* __restrict__ w1,
                                                   const float* __restrict__ w2,
                                                   unsigned short* __restrict__ W1T,
                                                   unsigned short* __restrict__ W2T,
                                                   const float* __restrict__ x,
                                                   const float* __restrict__ a_down,
                                                   const int* __restrict__ idxp,
                                                   float* __restrict__ lmid,
                                                   unsigned short* __restrict__ Xb) {
  __shared__ __align__(16) char pmem[36864];
  const int bid = blockIdx.x;
  const int t = threadIdx.x;

  if (bid < 8192) {
    const float* in;
    unsigned short* out;
    int rows, cols, bx, by;
    if (bid < 4096) {
      in = w1; out = W1T; rows = 1024; cols = 4096;
      bx = bid & 127; by = bid >> 7;
    } else {
      in = w2; out = W2T; rows = 4096; cols = 1024;
      const int b2 = bid - 4096;
      bx = b2 & 31; by = b2 >> 5;
    }
    float (*tile)[33] = (float(*)[33])pmem;
    const int c0 = bx * 32, r0 = by * 32;
    const int tx = t & 31, ty = t >> 5;
#pragma unroll
    for (int j = 0; j < 32; j += 8)
      tile[ty + j][tx] = in[(size_t)(r0 + ty + j) * cols + c0 + tx];
    __syncthreads();
#pragma unroll
    for (int j = 0; j < 32; j += 8)
      out[(size_t)(c0 + ty + j) * rows + r0 + tx] = f2bf(tile[tx][ty + j]);
    return;
  }

  float* ad = (float*)pmem;  // [1024*9]
  const float* A = a_down + (size_t)(*idxp) * (1024 * 8);
  for (int i = t; i < 2048; i += 256) {
    float4 v = ((const float4*)A)[i];
    int row = i >> 1, p = (i & 1) * 4;
    ad[row * 9 + p] = v.x; ad[row * 9 + p + 1] = v.y;
    ad[row * 9 + p + 2] = v.z; ad[row * 9 + p + 3] = v.w;
  }
  __syncthreads();
  const int j = bid - 8192;
  const int wid = t >> 6, lane = t & 63;
  const int row = j * 4 + wid;
  const float4* xr4 = (const float4*)(x + (size_t)row * 1024);
  ushort4* xbr4 = (ushort4*)(Xb + (size_t)row * 1024);
  float acc[8] = {0.f, 0.f, 0.f, 0.f, 0.f, 0.f, 0.f, 0.f};
#pragma unroll
  for (int c = 0; c < 4; ++c) {
    int i4 = c * 64 + lane;
    float4 xv = xr4[i4];
    ushort4 o;
    o.x = f2bf(xv.x); o.y = f2bf(xv.y); o.z = f2bf(xv.z); o.w = f2bf(xv.w);
    xbr4[i4] = o;
    const int kb = i4 * 4;
    const float xs[4] = {xv.x, xv.y, xv.z, xv.w};
#pragma unroll
    for (int jj = 0; jj < 4; ++jj)
#pragma unroll
      for (int r = 0; r < 8; ++r) acc[r] += xs[jj] * ad[(kb + jj) * 9 + r];
  }
#pragma unroll
  for (int off = 32; off > 0; off >>= 1) {
#pragma unroll
    for (int r = 0; r < 8; ++r) acc[r] += __shfl_xor(acc[r], off);
  }
  if (lane == 0) {
    *(float4*)(lmid + (size_t)row * 8) = make_float4(acc[0], acc[1], acc[2], acc[3]);
    *(float4*)(lmid + (size_t)row * 8 + 4) = make_float4(acc[4], acc[5], acc[6], acc[7]);
  }
}

// ===== 8-wave 256x128 GEMM K-loop (BK=32), 3x24KiB rotation, T3+T4.
// R23: wave split 2m x 4n (wave owns 64x64: 4 A-frags + 4 B-frags = 8 ds_read_b128/step
// vs R22's 1m x 8n = 10; per-block reads 80 -> 64). Theory: 72% of gemm2's time is
// non-MFMA; 80 b128 x ~12cyc x 2 blocks ~= 1920 cyc/CU-step is the dominant stall (LDS
// read throughput), so cutting redundant B reads 20% attacks it directly. Staging,
// swizzle, vmcnt schedule byte-identical to R22 (proven). acc[4][4]=64 + frags 32 < 128.

// ------- GEMM1: H = gelu(Xb . W1T^T + b1), bf16 out. 512 thr, grid 2048 -------
__global__ __launch_bounds__(512) void gemm1_gelu_kernel(const unsigned short* __restrict__ A,
                                                         const unsigned short* __restrict__ B,
                                                         const float* __restrict__ bias,
                                                         unsigned short* __restrict__ H) {
  extern __shared__ char smem[];  // 73728 B
  const int t = threadIdx.x;
  const int w = t >> 6, lane = t & 63, lr = lane & 15, kg = lane >> 4;
  const int kgx = kg ^ ((lr >> 1) & 3);
  const int wm = w >> 1, wn = w & 1;
  constexpr int LD = 1024, NKT = 32;

  // per-XCD 8x8 squares: M-tiles 64, N-tiles 32.
  const int bid = blockIdx.x;
  const int xcd = bid & 7, j = bid >> 3;   // j 0..255
  const int sq = j >> 6, i = j & 63;       // sq 0..3
  const size_t m0 = (size_t)(xcd * 8 + (i & 7)) * 256;
  const size_t n0 = (size_t)(sq * 8 + (i >> 3)) * 128;

  const int sr = w * 16 + (lane >> 2);
  const int scol = ((t & 3) ^ ((sr >> 1) & 3)) * 8;
  const unsigned short* gA0 = A + (m0 + sr) * LD + scol;
  const unsigned short* gA1 = A + (m0 + 128 + sr) * LD + scol;
  const unsigned short* gB = B + (n0 + sr) * LD + scol;
  const unsigned wOff = (unsigned)(w << 10);

#define STAGE1(bufb, ko)                              \
  do {                                                \
    gload16(gA0 + (ko), smem + (bufb) + wOff);        \
    gload16(gA1 + (ko), smem + (bufb) + 8192 + wOff); \
    gload16(gB + (ko), smem + (bufb) + 16384 + wOff); \
  } while (0)

  floatx4 acc[4][4] = {};

  STAGE1(0u, 0);
  STAGE1(24576u, 32);
  WAIT_VM(3);
  S_BARRIER();

  unsigned cur = 0u, stg = 49152u;
#pragma unroll 1
  for (int kt = 0; kt < NKT; ++kt) {
    if (kt + 2 < NKT) STAGE1(stg, (kt + 2) * 32);
    const unsigned short* As = (const unsigned short*)(smem + cur);
    const unsigned short* Bs = (const unsigned short*)(smem + cur + 16384);
    bfloatx8 af[4], bf[4];
#pragma unroll
    for (int mi = 0; mi < 4; ++mi)
      af[mi] = *(const bfloatx8*)(As + (unsigned)(wm * 64 + mi * 16 + lr) * 32 + (unsigned)kgx * 8);
#pragma unroll
    for (int ni = 0; ni < 4; ++ni)
      bf[ni] = *(const bfloatx8*)(Bs + (unsigned)(wn * 64 + ni * 16 + lr) * 32 + (unsigned)kgx * 8);
#pragma unroll
    for (int mi = 0; mi < 4; ++mi)
#pragma unroll
      for (int ni = 0; ni < 4; ++ni)
        acc[mi][ni] = __builtin_amdgcn_mfma_f32_16x16x32_bf16(af[mi], bf[ni], acc[mi][ni], 0, 0, 0);
    if (kt + 2 < NKT) { WAIT_VM(3); } else { WAIT_VM(0); }
    S_BARRIER();
    cur = (cur == 49152u) ? 0u : cur + 24576u;
    stg = (stg == 49152u) ? 0u : stg + 24576u;
  }
#undef STAGE1

  // epilogue: 4 rounds (mi), sE[64][ESTR] f32; per round 16-wide gelu+bf16 stores.
  // Fragment (mi,ni): sE[(wm*16 + kg*4+r)*ESTR + wn*64 + ni*16 + lr]; global row
  // gm = m0 + (s>>4)*64 + mi*16 + (s&15) for sE row s.
  __syncthreads();
  float* sE = (float*)smem;
  const int erow = t >> 3, ec0 = (t & 7) * 16;
#pragma unroll
  for (int mi = 0; mi < 4; ++mi) {
#pragma unroll
    for (int ni = 0; ni < 4; ++ni)
#pragma unroll
      for (int r = 0; r < 4; ++r)
        sE[(wm * 16 + kg * 4 + r) * ESTR + wn * 64 + ni * 16 + lr] = acc[mi][ni][r];
    __syncthreads();
    const size_t gm = m0 + (size_t)(erow >> 4) * 64 + mi * 16 + (erow & 15);
    const int gc = (int)n0 + ec0;
    const float* src = sE + erow * ESTR + ec0;
    alignas(16) unsigned short pk[16];
#pragma unroll
    for (int i2 = 0; i2 < 16; ++i2) {
      float v = src[i2] + bias[gc + i2];
      float g = 0.5f * v * (1.0f + erff(v * 0.70710678118654752440f));
      pk[i2] = f2bf(g);
    }
    *(ushortx8*)(H + gm * 4096 + gc) = *(const ushortx8*)&pk[0];
    *(ushortx8*)(H + gm * 4096 + gc + 8) = *(const ushortx8*)&pk[8];
    __syncthreads();
  }
}

// --- GEMM2: OUT = H . W2T^T + b2 + lora, f32 out. 512 thr, grid 512 ---
__global__ __launch_bounds__(512) void gemm2_out_kernel(const unsigned short* __restrict__ A,
                                                        const unsigned short* __restrict__ B,
                                                        const float* __restrict__ bias,
                                                        const float* __restrict__ lmid,
                                                        const float* __restrict__ a_up,
                                                        const int* __restrict__ idxp,
                                                        float* __restrict__ OUT) {
  extern __shared__ char smem[];  // 73728 B
  const int t = threadIdx.x;
  const int w = t >> 6, lane = t & 63, lr = lane & 15, kg = lane >> 4;
  const int kgx = kg ^ ((lr >> 1) & 3);
  const int wm = w >> 1, wn = w & 1;
  constexpr int LD = 4096, NKT = 128;

  const int bid = blockIdx.x;
  const int xcd = bid & 7, j = bid >> 3;
  const size_t m0 = (size_t)(xcd * 8 + (j >> 3)) * 256;
  const size_t n0 = (size_t)(j & 7) * 128;

  const int sr = w * 16 + (lane >> 2);
  const int scol = ((t & 3) ^ ((sr >> 1) & 3)) * 8;
  const unsigned short* gA0 = A + (m0 + sr) * LD + scol;
  const unsigned short* gA1 = A + (m0 + 128 + sr) * LD + scol;
  const unsigned short* gB = B + (n0 + sr) * LD + scol;
  const unsigned wOff = (unsigned)(w << 10);

#define STAGE2(bufb, ko)                              \
  do {                                                \
    gload16(gA0 + (ko), smem + (bufb) + wOff);        \
    gload16(gA1 + (ko), smem + (bufb) + 8192 + wOff); \
    gload16(gB + (ko), smem + (bufb) + 16384 + wOff); \
  } while (0)

  floatx4 acc[4][4] = {};

  STAGE2(0u, 0);
  STAGE2(24576u, 32);
  WAIT_VM(3);
  S_BARRIER();

  unsigned cur = 0u, stg = 49152u;
#pragma unroll 1
  for (int kt = 0; kt < NKT; ++kt) {
    if (kt + 2 < NKT) STAGE2(stg, (kt + 2) * 32);
    const unsigned short* As = (const unsigned short*)(smem + cur);
    const unsigned short* Bs = (const unsigned short*)(smem + cur + 16384);
    bfloatx8 af[4], bf[4];
#pragma unroll
    for (int mi = 0; mi < 4; ++mi)
      af[mi] = *(const bfloatx8*)(As + (unsigned)(wm * 64 + mi * 16 + lr) * 32 + (unsigned)kgx * 8);
#pragma unroll
    for (int ni = 0; ni < 4; ++ni)
      bf[ni] = *(const bfloatx8*)(Bs + (unsigned)(wn * 64 + ni * 16 + lr) * 32 + (unsigned)kgx * 8);
#pragma unroll
    for (int mi = 0; mi < 4; ++mi)
#pragma unroll
      for (int ni = 0; ni < 4; ++ni)
        acc[mi][ni] = __builtin_amdgcn_mfma_f32_16x16x32_bf16(af[mi], bf[ni], acc[mi][ni], 0, 0, 0);
    if (kt + 2 < NKT) { WAIT_VM(3); } else { WAIT_VM(0); }
    S_BARRIER();
    cur = (cur == 49152u) ? 0u : cur + 24576u;
    stg = (stg == 49152u) ? 0u : stg + 24576u;
  }
#undef STAGE2

  __syncthreads();
  float* sE = (float*)smem;
  const float* aup = a_up + (size_t)(*idxp) * 8192;
  const int erow = t >> 3, ec0 = (t & 7) * 16;
#pragma unroll
  for (int mi = 0; mi < 4; ++mi) {
#pragma unroll
    for (int ni = 0; ni < 4; ++ni)
#pragma unroll
      for (int r = 0; r < 4; ++r)
        sE[(wm * 16 + kg * 4 + r) * ESTR + wn * 64 + ni * 16 + lr] = acc[mi][ni][r];
    __syncthreads();
    const size_t gm = m0 + (size_t)(erow >> 4) * 64 + mi * 16 + (erow & 15);
    const int gc = (int)n0 + ec0;
    const float* src = sE + erow * ESTR + ec0;
    alignas(16) float lmv[8];
    *(float4*)&lmv[0] = *(const float4*)(lmid + gm * 8);
    *(float4*)&lmv[4] = *(const float4*)(lmid + gm * 8 + 4);
    alignas(16) float v[16];
#pragma unroll
    for (int i2 = 0; i2 < 16; ++i2) v[i2] = src[i2] + bias[gc + i2];
#pragma unroll
    for (int r = 0; r < 8; ++r) {
      const float lw = lmv[r];
      const float* ar = aup + r * 1024 + gc;
#pragma unroll
      for (int i2 = 0; i2 < 16; ++i2) v[i2] += lw * ar[i2];
    }
#pragma unroll
    for (int i2 = 0; i2 < 16; i2 += 4)
      *(float4*)(OUT + gm * 1024 + gc + i2) = *(const float4*)&v[i2];
    __syncthreads();
  }
}

extern "C" void kernel_launch(void* const* d_in, const int* in_sizes, int n_in,
                              void* d_out, int out_size, void* d_ws, size_t ws_size,
                              hipStream_t stream) {
  const float* x      = (const float*)d_in[0];
  const float* w1     = (const float*)d_in[1];
  const float* b1     = (const float*)d_in[2];
  const float* w2     = (const float*)d_in[3];
  const float* b2     = (const float*)d_in[4];
  const float* a_down = (const float*)d_in[5];
  const float* a_up   = (const float*)d_in[6];
  const int*   idx    = (const int*)d_in[7];
  float* out = (float*)d_out;

  char* ws = (char*)d_ws;
  unsigned short* Xb  = (unsigned short*)(ws);              // 16384x1024 bf16 = 32 MiB
  unsigned short* W1T = (unsigned short*)(ws + 33554432);   // 4096x1024 bf16 = 8 MiB
  unsigned short* W2T = (unsigned short*)(ws + 41943040);   // 1024x4096 bf16 = 8 MiB
  float*          LMID = (float*)(ws + 50331648);           // 16384x8 f32 = 0.5 MiB
  unsigned short* H   = (unsigned short*)(ws + 50855936);   // 16384x4096 bf16 = 128 MiB

  (void)hipFuncSetAttribute((const void*)gemm1_gelu_kernel, hipFuncAttributeMaxDynamicSharedMemorySize, 73728);
  (void)hipFuncSetAttribute((const void*)gemm2_out_kernel, hipFuncAttributeMaxDynamicSharedMemorySize, 73728);

  prep_kernel<<<12288, 256, 0, stream>>>(w1, w2, W1T, W2T, x, a_down, idx, LMID, Xb);
  gemm1_gelu_kernel<<<2048, 512, 73728, stream>>>(Xb, W1T, b1, H);
  gemm2_out_kernel<<<512, 512, 73728, stream>>>(H, W2T, b2, LMID, a_up, idx, out);
}

// Round 24
// 411.423 us; speedup vs baseline: 1.0122x; 1.0122x over previous
//
#include <hip/hip_runtime.h>
#include <hip/hip_bf16.h>
#include <math.h>

typedef __attribute__((ext_vector_type(4))) float floatx4;
typedef __attribute__((ext_vector_type(8))) __bf16 bfloatx8;
typedef __attribute__((ext_vector_type(8))) unsigned short ushortx8;

static __device__ __forceinline__ unsigned short f2bf(float f) {
  __hip_bfloat16 h = __float2bfloat16(f);
  return *reinterpret_cast<unsigned short*>(&h);
}

static __device__ __forceinline__ void gload16(const void* g, void* l) {
  __builtin_amdgcn_global_load_lds(
      (const __attribute__((address_space(1))) unsigned int*)g,
      (__attribute__((address_space(3))) unsigned int*)l, 16, 0, 0);
}

#define S_BARRIER() __builtin_amdgcn_s_barrier()
#define WAIT_VM(n)  do { asm volatile("s_waitcnt vmcnt(" #n ")" ::: "memory"); __builtin_amdgcn_sched_barrier(0); } while (0)

// sE row stride (f32) for GEMM epilogues (R18/R19: epilogue bank conflicts; 132 = 2-way
// writes, 4-way reads, 16B-aligned rows; 128*132*4 = 67584 <= 73728).
#define ESTR 132

// ===== fused prep: [0,4096) w1-transpose, [4096,8192) w2-transpose, [8192,12288) lora =====
__global__ __launch_bounds__(256) void prep_kernel(const float* __restrict__ w1,
                                                   const float* __restrict__ w2,
                                                   unsigned short* __restrict__ W1T,
                                                   unsigned short* __restrict__ W2T,
                                                   const float* __restrict__ x,
                                                   const float* __restrict__ a_down,
                                                   const int* __restrict__ idxp,
                                                   float* __restrict__ lmid,
                                                   unsigned short* __restrict__ Xb) {
  __shared__ __align__(16) char pmem[36864];
  const int bid = blockIdx.x;
  const int t = threadIdx.x;

  if (bid < 8192) {
    // transpose + cast: out[c][r] = bf16(in[r][c])
    const float* in;
    unsigned short* out;
    int rows, cols, bx, by;
    if (bid < 4096) {
      in = w1; out = W1T; rows = 1024; cols = 4096;
      bx = bid & 127; by = bid >> 7;          // grid (128, 32)
    } else {
      in = w2; out = W2T; rows = 4096; cols = 1024;
      const int b2 = bid - 4096;
      bx = b2 & 31; by = b2 >> 5;             // grid (32, 128)
    }
    float (*tile)[33] = (float(*)[33])pmem;
    const int c0 = bx * 32, r0 = by * 32;
    const int tx = t & 31, ty = t >> 5;
#pragma unroll
    for (int j = 0; j < 32; j += 8)
      tile[ty + j][tx] = in[(size_t)(r0 + ty + j) * cols + c0 + tx];
    __syncthreads();
#pragma unroll
    for (int j = 0; j < 32; j += 8)
      out[(size_t)(c0 + ty + j) * rows + r0 + tx] = f2bf(tile[tx][ty + j]);
    return;
  }

  // lora_mid + x->bf16 fused, vectorized
  float* ad = (float*)pmem;  // [1024*9] padded stride 9
  const float* A = a_down + (size_t)(*idxp) * (1024 * 8);
  for (int i = t; i < 2048; i += 256) {
    float4 v = ((const float4*)A)[i];
    int row = i >> 1, p = (i & 1) * 4;
    ad[row * 9 + p] = v.x; ad[row * 9 + p + 1] = v.y;
    ad[row * 9 + p + 2] = v.z; ad[row * 9 + p + 3] = v.w;
  }
  __syncthreads();
  const int j = bid - 8192;
  const int wid = t >> 6, lane = t & 63;
  const int row = j * 4 + wid;
  const float4* xr4 = (const float4*)(x + (size_t)row * 1024);
  ushort4* xbr4 = (ushort4*)(Xb + (size_t)row * 1024);
  float acc[8] = {0.f, 0.f, 0.f, 0.f, 0.f, 0.f, 0.f, 0.f};
#pragma unroll
  for (int c = 0; c < 4; ++c) {
    int i4 = c * 64 + lane;
    float4 xv = xr4[i4];
    ushort4 o;
    o.x = f2bf(xv.x); o.y = f2bf(xv.y); o.z = f2bf(xv.z); o.w = f2bf(xv.w);
    xbr4[i4] = o;
    const int kb = i4 * 4;
    const float xs[4] = {xv.x, xv.y, xv.z, xv.w};
#pragma unroll
    for (int jj = 0; jj < 4; ++jj)
#pragma unroll
      for (int r = 0; r < 8; ++r) acc[r] += xs[jj] * ad[(kb + jj) * 9 + r];
  }
#pragma unroll
  for (int off = 32; off > 0; off >>= 1) {
#pragma unroll
    for (int r = 0; r < 8; ++r) acc[r] += __shfl_xor(acc[r], off);
  }
  if (lane == 0) {
    *(float4*)(lmid + (size_t)row * 8) = make_float4(acc[0], acc[1], acc[2], acc[3]);
    *(float4*)(lmid + (size_t)row * 8 + 4) = make_float4(acc[4], acc[5], acc[6], acc[7]);
  }
}

// ===== 8-wave 256x128 GEMM K-loop (BK=32), 3x24KiB rotation, T3+T4 (R17-R22 proven) =====

// ------- GEMM1: H = gelu(Xb . W1T^T + b1), bf16 out. 512 thr, grid 2048 -------
__global__ __launch_bounds__(512) void gemm1_gelu_kernel(const unsigned short* __restrict__ A,
                                                         const unsigned short* __restrict__ B,
                                                         const float* __restrict__ bias,
                                                         unsigned short* __restrict__ H) {
  extern __shared__ char smem[];  // 73728 B
  const int t = threadIdx.x;
  const int w = t >> 6, lane = t & 63, lr = lane & 15, kg = lane >> 4;
  const int kgx = kg ^ ((lr >> 1) & 3);
  constexpr int LD = 1024, NKT = 32;

  // per-XCD 8x8 squares: M-tiles 64, N-tiles 32.
  const int bid = blockIdx.x;
  const int xcd = bid & 7, j = bid >> 3;   // j 0..255
  const int sq = j >> 6, i = j & 63;       // sq 0..3
  const size_t m0 = (size_t)(xcd * 8 + (i & 7)) * 256;
  const size_t n0 = (size_t)(sq * 8 + (i >> 3)) * 128;

  const int sr = w * 16 + (lane >> 2);
  const int scol = ((t & 3) ^ ((sr >> 1) & 3)) * 8;
  const unsigned short* gA0 = A + (m0 + sr) * LD + scol;
  const unsigned short* gA1 = A + (m0 + 128 + sr) * LD + scol;
  const unsigned short* gB = B + (n0 + sr) * LD + scol;
  const unsigned wOff = (unsigned)(w << 10);

#define STAGE1(bufb, ko)                              \
  do {                                                \
    gload16(gA0 + (ko), smem + (bufb) + wOff);        \
    gload16(gA1 + (ko), smem + (bufb) + 8192 + wOff); \
    gload16(gB + (ko), smem + (bufb) + 16384 + wOff); \
  } while (0)

  floatx4 acc[2][8] = {};

  STAGE1(0u, 0);
  STAGE1(24576u, 32);
  WAIT_VM(3);
  S_BARRIER();

  unsigned cur = 0u, stg = 49152u;
#pragma unroll 1
  for (int kt = 0; kt < NKT; ++kt) {
    if (kt + 2 < NKT) STAGE1(stg, (kt + 2) * 32);
    const unsigned short* As = (const unsigned short*)(smem + cur);
    const unsigned short* Bs = (const unsigned short*)(smem + cur + 16384);
    bfloatx8 af[2];
#pragma unroll
    for (int mi = 0; mi < 2; ++mi)
      af[mi] = *(const bfloatx8*)(As + (unsigned)(w * 32 + mi * 16 + lr) * 32 + (unsigned)kgx * 8);
    {
      bfloatx8 bfA[4];
#pragma unroll
      for (int ni = 0; ni < 4; ++ni)
        bfA[ni] = *(const bfloatx8*)(Bs + (unsigned)(ni * 16 + lr) * 32 + (unsigned)kgx * 8);
#pragma unroll
      for (int mi = 0; mi < 2; ++mi)
#pragma unroll
        for (int ni = 0; ni < 4; ++ni)
          acc[mi][ni] = __builtin_amdgcn_mfma_f32_16x16x32_bf16(af[mi], bfA[ni], acc[mi][ni], 0, 0, 0);
    }
    {
      bfloatx8 bfB[4];
#pragma unroll
      for (int ni = 0; ni < 4; ++ni)
        bfB[ni] = *(const bfloatx8*)(Bs + (unsigned)((ni + 4) * 16 + lr) * 32 + (unsigned)kgx * 8);
#pragma unroll
      for (int mi = 0; mi < 2; ++mi)
#pragma unroll
        for (int ni = 0; ni < 4; ++ni)
          acc[mi][4 + ni] = __builtin_amdgcn_mfma_f32_16x16x32_bf16(af[mi], bfB[ni], acc[mi][4 + ni], 0, 0, 0);
    }
    if (kt + 2 < NKT) { WAIT_VM(3); } else { WAIT_VM(0); }
    S_BARRIER();
    cur = (cur == 49152u) ? 0u : cur + 24576u;
    stg = (stg == 49152u) ? 0u : stg + 24576u;
  }
#undef STAGE1

  // epilogue: 2 rounds (mi), sE[128][ESTR] f32; per round 2 half-rounds of 16-wide gelu+bf16.
  __syncthreads();
  float* sE = (float*)smem;
  const int erow = t >> 3, ec0 = (t & 7) * 16;
#pragma unroll
  for (int mi = 0; mi < 2; ++mi) {
#pragma unroll
    for (int ni = 0; ni < 8; ++ni)
#pragma unroll
      for (int r = 0; r < 4; ++r)
        sE[(w * 16 + kg * 4 + r) * ESTR + ni * 16 + lr] = acc[mi][ni][r];
    __syncthreads();
#pragma unroll
    for (int h = 0; h < 2; ++h) {
      const int row = erow + h * 64;
      const size_t gm = m0 + (size_t)(row >> 4) * 32 + mi * 16 + (row & 15);
      const int gc = (int)n0 + ec0;
      const float* src = sE + row * ESTR + ec0;
      alignas(16) unsigned short pk[16];
#pragma unroll
      for (int i2 = 0; i2 < 16; ++i2) {
        float v = src[i2] + bias[gc + i2];
        float g = 0.5f * v * (1.0f + erff(v * 0.70710678118654752440f));
        pk[i2] = f2bf(g);
      }
      *(ushortx8*)(H + gm * 4096 + gc) = *(const ushortx8*)&pk[0];
      *(ushortx8*)(H + gm * 4096 + gc + 8) = *(const ushortx8*)&pk[8];
    }
    __syncthreads();
  }
}

// --- GEMM2: OUT = H . W2T^T + b2 + lora, f32 out. 512 thr, grid 512 ---
__global__ __launch_bounds__(512) void gemm2_out_kernel(const unsigned short* __restrict__ A,
                                                        const unsigned short* __restrict__ B,
                                                        const float* __restrict__ bias,
                                                        const float* __restrict__ lmid,
                                                        const float* __restrict__ a_up,
                                                        const int* __restrict__ idxp,
                                                        float* __restrict__ OUT) {
  extern __shared__ char smem[];  // 73728 B
  const int t = threadIdx.x;
  const int w = t >> 6, lane = t & 63, lr = lane & 15, kg = lane >> 4;
  const int kgx = kg ^ ((lr >> 1) & 3);
  constexpr int LD = 4096, NKT = 128;

  const int bid = blockIdx.x;
  const int xcd = bid & 7, j = bid >> 3;
  const size_t m0 = (size_t)(xcd * 8 + (j >> 3)) * 256;
  const size_t n0 = (size_t)(j & 7) * 128;

  const int sr = w * 16 + (lane >> 2);
  const int scol = ((t & 3) ^ ((sr >> 1) & 3)) * 8;
  const unsigned short* gA0 = A + (m0 + sr) * LD + scol;
  const unsigned short* gA1 = A + (m0 + 128 + sr) * LD + scol;
  const unsigned short* gB = B + (n0 + sr) * LD + scol;
  const unsigned wOff = (unsigned)(w << 10);

#define STAGE2(bufb, ko)                              \
  do {                                                \
    gload16(gA0 + (ko), smem + (bufb) + wOff);        \
    gload16(gA1 + (ko), smem + (bufb) + 8192 + wOff); \
    gload16(gB + (ko), smem + (bufb) + 16384 + wOff); \
  } while (0)

  floatx4 acc[2][8] = {};

  STAGE2(0u, 0);
  STAGE2(24576u, 32);
  WAIT_VM(3);
  S_BARRIER();

  unsigned cur = 0u, stg = 49152u;
#pragma unroll 1
  for (int kt = 0; kt < NKT; ++kt) {
    if (kt + 2 < NKT) STAGE2(stg, (kt + 2) * 32);
    const unsigned short* As = (const unsigned short*)(smem + cur);
    const unsigned short* Bs = (const unsigned short*)(smem + cur + 16384);
    bfloatx8 af[2];
#pragma unroll
    for (int mi = 0; mi < 2; ++mi)
      af[mi] = *(const bfloatx8*)(As + (unsigned)(w * 32 + mi * 16 + lr) * 32 + (unsigned)kgx * 8);
    {
      bfloatx8 bfA[4];
#pragma unroll
      for (int ni = 0; ni < 4; ++ni)
        bfA[ni] = *(const bfloatx8*)(Bs + (unsigned)(ni * 16 + lr) * 32 + (unsigned)kgx * 8);
#pragma unroll
      for (int mi = 0; mi < 2; ++mi)
#pragma unroll
        for (int ni = 0; ni < 4; ++ni)
          acc[mi][ni] = __builtin_amdgcn_mfma_f32_16x16x32_bf16(af[mi], bfA[ni], acc[mi][ni], 0, 0, 0);
    }
    {
      bfloatx8 bfB[4];
#pragma unroll
      for (int ni = 0; ni < 4; ++ni)
        bfB[ni] = *(const bfloatx8*)(Bs + (unsigned)((ni + 4) * 16 + lr) * 32 + (unsigned)kgx * 8);
#pragma unroll
      for (int mi = 0; mi < 2; ++mi)
#pragma unroll
        for (int ni = 0; ni < 4; ++ni)
          acc[mi][4 + ni] = __builtin_amdgcn_mfma_f32_16x16x32_bf16(af[mi], bfB[ni], acc[mi][4 + ni], 0, 0, 0);
    }
    if (kt + 2 < NKT) { WAIT_VM(3); } else { WAIT_VM(0); }
    S_BARRIER();
    cur = (cur == 49152u) ? 0u : cur + 24576u;
    stg = (stg == 49152u) ? 0u : stg + 24576u;
  }
#undef STAGE2

  __syncthreads();
  float* sE = (float*)smem;
  const float* aup = a_up + (size_t)(*idxp) * 8192;
  const int erow = t >> 3, ec0 = (t & 7) * 16;
#pragma unroll
  for (int mi = 0; mi < 2; ++mi) {
#pragma unroll
    for (int ni = 0; ni < 8; ++ni)
#pragma unroll
      for (int r = 0; r < 4; ++r)
        sE[(w * 16 + kg * 4 + r) * ESTR + ni * 16 + lr] = acc[mi][ni][r];
    __syncthreads();
#pragma unroll
    for (int h = 0; h < 2; ++h) {
      const int row = erow + h * 64;
      const size_t gm = m0 + (size_t)(row >> 4) * 32 + mi * 16 + (row & 15);
      const int gc = (int)n0 + ec0;
      const float* src = sE + row * ESTR + ec0;
      alignas(16) float lmv[8];
      *(float4*)&lmv[0] = *(const float4*)(lmid + gm * 8);
      *(float4*)&lmv[4] = *(const float4*)(lmid + gm * 8 + 4);
      alignas(16) float v[16];
#pragma unroll
      for (int i2 = 0; i2 < 16; ++i2) v[i2] = src[i2] + bias[gc + i2];
#pragma unroll
      for (int r = 0; r < 8; ++r) {
        const float lw = lmv[r];
        const float* ar = aup + r * 1024 + gc;
#pragma unroll
        for (int i2 = 0; i2 < 16; ++i2) v[i2] += lw * ar[i2];
      }
#pragma unroll
      for (int i2 = 0; i2 < 16; i2 += 4)
        *(float4*)(OUT + gm * 1024 + gc + i2) = *(const float4*)&v[i2];
    }
    __syncthreads();
  }
}

extern "C" void kernel_launch(void* const* d_in, const int* in_sizes, int n_in,
                              void* d_out, int out_size, void* d_ws, size_t ws_size,
                              hipStream_t stream) {
  const float* x      = (const float*)d_in[0];
  const float* w1     = (const float*)d_in[1];
  const float* b1     = (const float*)d_in[2];
  const float* w2     = (const float*)d_in[3];
  const float* b2     = (const float*)d_in[4];
  const float* a_down = (const float*)d_in[5];
  const float* a_up   = (const float*)d_in[6];
  const int*   idx    = (const int*)d_in[7];
  float* out = (float*)d_out;

  char* ws = (char*)d_ws;
  unsigned short* Xb  = (unsigned short*)(ws);              // 16384x1024 bf16 = 32 MiB
  unsigned short* W1T = (unsigned short*)(ws + 33554432);   // 4096x1024 bf16 = 8 MiB
  unsigned short* W2T = (unsigned short*)(ws + 41943040);   // 1024x4096 bf16 = 8 MiB
  float*          LMID = (float*)(ws + 50331648);           // 16384x8 f32 = 0.5 MiB
  unsigned short* H   = (unsigned short*)(ws + 50855936);   // 16384x4096 bf16 = 128 MiB

  (void)hipFuncSetAttribute((const void*)gemm1_gelu_kernel, hipFuncAttributeMaxDynamicSharedMemorySize, 73728);
  (void)hipFuncSetAttribute((const void*)gemm2_out_kernel, hipFuncAttributeMaxDynamicSharedMemorySize, 73728);

  prep_kernel<<<12288, 256, 0, stream>>>(w1, w2, W1T, W2T, x, a_down, idx, LMID, Xb);
  gemm1_gelu_kernel<<<2048, 512, 73728, stream>>>(Xb, W1T, b1, H);
  gemm2_out_kernel<<<512, 512, 73728, stream>>>(H, W2T, b2, LMID, a_up, idx, out);
}